// Round 5
// baseline (46.862 us; speedup 1.0000x reference)
//
#include <hip/hip_runtime.h>

// out[b,s,d] = x[b,s,d] + pe[s,d]
//   d < 512 : pe = sin(s * 10000^(-2d/1024))
//   d >= 512: pe = cos(s * 10000^(-(2*(d-512)+1)/1024))
// B=8, S=4096, D=1024, fp32.
// Memory-bound: 268 MB logical traffic -> ~43us floor at 6.3 TB/s copy ceiling.
// R3: nontemporal store = no effect (MALL allocation is memory-side). Reverted.
// R4: explicit 8-deep load MLP: 49.8 -> 46.5 us.
// R5: 2x grid (8192 blocks, 4 batch rows/thread) — same chip-wide MLP,
// 2x waves, shorter per-block chain; probing concurrency vs HBM limit.

typedef float floatx4 __attribute__((ext_vector_type(4)));

__global__ __launch_bounds__(256) void pe_add_kernel(const floatx4* __restrict__ x,
                                                     floatx4* __restrict__ out) {
    constexpr int S = 4096;
    constexpr int BH = 4;                 // batch rows per thread (half of 8)
    constexpr int ROW4 = 1024 / 4;        // float4s per row = 256

    const int bid = blockIdx.x;           // 0..8191
    const int s = bid >> 1;               // 0..4095
    const int bbase = (bid & 1) * BH;     // 0 or 4
    const int t = threadIdx.x;            // 0..255
    const int d0 = t * 4;

    const int rowbase = s * ROW4 + t;

    // Issue all 4 batch loads first — 4 global_load_dwordx4 in flight per lane.
    floatx4 v[BH];
    #pragma unroll
    for (int b = 0; b < BH; ++b) {
        v[b] = x[(bbase + b) * (S * ROW4) + rowbase];
    }

    // pe computed once per thread while loads are in flight.
    const float pos = (float)s;
    const float NLOG2_10000_OVER_D = -13.287712379549449f * (1.0f / 1024.0f);

    // 512 % 4 == 0 -> all 4 lanes of this thread are on the same side.
    float pe[4];
    if (d0 < 512) {
        #pragma unroll
        for (int j = 0; j < 4; ++j) {
            const float k = 2.0f * (float)(d0 + j);
            const float invfreq = exp2f(k * NLOG2_10000_OVER_D);
            pe[j] = sinf(pos * invfreq);
        }
    } else {
        #pragma unroll
        for (int j = 0; j < 4; ++j) {
            const float k = 2.0f * (float)(d0 - 512 + j) + 1.0f;
            const float invfreq = exp2f(k * NLOG2_10000_OVER_D);
            pe[j] = cosf(pos * invfreq);
        }
    }

    #pragma unroll
    for (int b = 0; b < BH; ++b) {
        floatx4 r = v[b];
        r.x += pe[0];
        r.y += pe[1];
        r.z += pe[2];
        r.w += pe[3];
        out[(bbase + b) * (S * ROW4) + rowbase] = r;
    }
}

extern "C" void kernel_launch(void* const* d_in, const int* in_sizes, int n_in,
                              void* d_out, int out_size, void* d_ws, size_t ws_size,
                              hipStream_t stream) {
    const floatx4* x = (const floatx4*)d_in[0];
    floatx4* out = (floatx4*)d_out;
    // grid: two blocks per s-row (batch halves)
    pe_add_kernel<<<dim3(8192), dim3(256), 0, stream>>>(x, out);
}